// Round 9
// baseline (1159.035 us; speedup 1.0000x reference)
//
#include <hip/hip_runtime.h>
#include <hip/hip_bf16.h>
#include <math.h>

#define D_ 1536
#define S_ 1024
#define B_ 4
#define H_ 12
#define HD_ 128
#define MAXC_ 256

typedef __bf16 bf16x8_t __attribute__((ext_vector_type(8)));
typedef float f32x4_t __attribute__((ext_vector_type(4)));

__device__ __forceinline__ float gelu_f(float v) {
    return 0.5f * v * (1.0f + erff(v / 1.41421356237f));
}

__device__ __forceinline__ void split2(float a, __hip_bfloat16& h, __hip_bfloat16& l) {
    h = __float2bfloat16(a);
    l = __float2bfloat16(a - __bfloat162float(h));
}

// bijective XCD swizzle (m204)
__device__ __forceinline__ void xcd_swizzle(int& bx, int& by, int gx, int gy) {
    int nwg = gx * gy;
    int orig = by * gx + bx;
    int xcd = orig & 7;
    int q = nwg >> 3, r = nwg & 7;
    int wg = (xcd < r ? xcd * (q + 1) : r * (q + 1) + (xcd - r) * q) + (orig >> 3);
    bx = wg % gx;
    by = wg / gx;
}

// ---------------- split-bf16 MFMA GEMM (BM=128/64) ---------------------------
// acc += Ah*Bh + Ah*Bl + Al*Bh; K-step 32.
// DBUF=0: single LDS buffer, 2 barriers/K-step, DEPTH-2 register prefetch
//         (tile i+2 issued at tile i => ~2 compute phases in flight, covers HBM).
// DBUF=1: double buffer, 1 barrier/K-step, depth-1 (proven for short-K).
// OUT: 0 = fp32 C, 1 = bf16 split-pair C, 2 = gelu + dot(w3) -> atomicAdd(lg)
template<int BM, int SPLITA, int SPLITB, int ACT, int OUT, int DBUF>
__global__ __launch_bounds__(256, 2)
void mfma3_gemm(const float* __restrict__ Af, const __hip_bfloat16* __restrict__ Ah,
                const __hip_bfloat16* __restrict__ Al,
                const float* __restrict__ Bf, const __hip_bfloat16* __restrict__ Bh,
                const __hip_bfloat16* __restrict__ Bl,
                const float* __restrict__ bias, int biasStride,
                float* __restrict__ Cf, __hip_bfloat16* __restrict__ Ch, __hip_bfloat16* __restrict__ Cl,
                const float* __restrict__ w3, float* __restrict__ lg,
                int K, int lda, int ldb, int ldc,
                long long aBound, long long azS, long long bzS, long long czS)
{
    constexpr int NB = DBUF ? 2 : 1;
    __shared__ __align__(16) __hip_bfloat16 Ash[NB][BM * 32], Asl[NB][BM * 32];
    __shared__ __align__(16) __hip_bfloat16 Bsh[NB][128 * 32], Bsl[NB][128 * 32];
    const int z = blockIdx.z;
    int bxi = blockIdx.x, byi = blockIdx.y;
    xcd_swizzle(bxi, byi, gridDim.x, gridDim.y);
    const int bm = byi * BM, bn = bxi * 128;
    const int tid = threadIdx.x, lane = tid & 63, wave = tid >> 6;
    const int wm = (BM == 128) ? (wave >> 1) : 0;
    const int wn = (BM == 128) ? (wave & 1) : wave;
    constexpr int NF = (BM == 128) ? 4 : 2;
    constexpr int WC = NF * 16;
    const int fr = lane & 15, kg = lane >> 4;
    f32x4_t acc[4][NF] = {};
    constexpr int RSH = (BM == 128) ? 1 : 2;
    constexpr int NBA = (BM == 128) ? 2 : 1;
    const int ar = tid >> RSH, akb = tid & ((1 << RSH) - 1);
    const int br = tid >> 1, bkb = tid & 1;

    // two independent staging register sets (compile-time indexed - no scratch)
    bf16x8_t rAh0[NBA], rAl0[NBA], rBh0[2], rBl0[2];
    bf16x8_t rAh1[NBA], rAl1[NBA], rBh1[2], rBl1[2];
    float4 rAf0[NBA][2], rBf0[2][2];
    float4 rAf1[NBA][2], rBf1[2][2];

#define LOAD_TILE(k0, rAh_, rAl_, rAf_, rBh_, rBl_, rBf_)                                       \
    {                                                                                           \
        _Pragma("unroll")                                                                       \
        for (int j = 0; j < NBA; ++j) {                                                         \
            int skg = akb * NBA + j;                                                            \
            long long base = (long long)(bm + ar) * lda + azS * z + (k0) + skg * 8;             \
            if (SPLITA) {                                                                       \
                _Pragma("unroll")                                                               \
                for (int q = 0; q < 2; ++q) {                                                   \
                    float4 v = make_float4(0.f, 0.f, 0.f, 0.f);                                 \
                    if (base + q * 4 + 4 <= aBound) v = *reinterpret_cast<const float4*>(&Af[base + q * 4]); \
                    rAf_[j][q] = v;                                                             \
                }                                                                               \
            } else {                                                                            \
                rAh_[j] = *reinterpret_cast<const bf16x8_t*>(&Ah[base]);                        \
                rAl_[j] = *reinterpret_cast<const bf16x8_t*>(&Al[base]);                        \
            }                                                                                   \
        }                                                                                       \
        _Pragma("unroll")                                                                       \
        for (int j = 0; j < 2; ++j) {                                                           \
            int skg = bkb * 2 + j;                                                              \
            long long base = (long long)(bn + br) * ldb + bzS * z + (k0) + skg * 8;             \
            if (SPLITB) {                                                                       \
                _Pragma("unroll")                                                               \
                for (int q = 0; q < 2; ++q)                                                     \
                    rBf_[j][q] = *reinterpret_cast<const float4*>(&Bf[base + q * 4]);           \
            } else {                                                                            \
                rBh_[j] = *reinterpret_cast<const bf16x8_t*>(&Bh[base]);                        \
                rBl_[j] = *reinterpret_cast<const bf16x8_t*>(&Bl[base]);                        \
            }                                                                                   \
        }                                                                                       \
    }

#define WRITE_TILE(buf, rAh_, rAl_, rAf_, rBh_, rBl_, rBf_)                                     \
    {                                                                                           \
        _Pragma("unroll")                                                                       \
        for (int j = 0; j < NBA; ++j) {                                                         \
            int skg = akb * NBA + j;                                                            \
            int blk = ar * 4 + (skg ^ ((ar >> 1) & 3));                                         \
            if (SPLITA) {                                                                       \
                float av[8];                                                                    \
                *reinterpret_cast<float4*>(&av[0]) = rAf_[j][0];                                \
                *reinterpret_cast<float4*>(&av[4]) = rAf_[j][1];                                \
                __hip_bfloat16 hh[8], ll[8];                                                    \
                _Pragma("unroll")                                                               \
                for (int q = 0; q < 8; ++q) split2(av[q], hh[q], ll[q]);                        \
                *reinterpret_cast<bf16x8_t*>(&Ash[buf][blk * 8]) = *reinterpret_cast<bf16x8_t*>(hh); \
                *reinterpret_cast<bf16x8_t*>(&Asl[buf][blk * 8]) = *reinterpret_cast<bf16x8_t*>(ll); \
            } else {                                                                            \
                *reinterpret_cast<bf16x8_t*>(&Ash[buf][blk * 8]) = rAh_[j];                     \
                *reinterpret_cast<bf16x8_t*>(&Asl[buf][blk * 8]) = rAl_[j];                     \
            }                                                                                   \
        }                                                                                       \
        _Pragma("unroll")                                                                       \
        for (int j = 0; j < 2; ++j) {                                                           \
            int skg = bkb * 2 + j;                                                              \
            int blk = br * 4 + (skg ^ ((br >> 1) & 3));                                         \
            if (SPLITB) {                                                                       \
                float av[8];                                                                    \
                *reinterpret_cast<float4*>(&av[0]) = rBf_[j][0];                                \
                *reinterpret_cast<float4*>(&av[4]) = rBf_[j][1];                                \
                __hip_bfloat16 hh[8], ll[8];                                                    \
                _Pragma("unroll")                                                               \
                for (int q = 0; q < 8; ++q) split2(av[q], hh[q], ll[q]);                        \
                *reinterpret_cast<bf16x8_t*>(&Bsh[buf][blk * 8]) = *reinterpret_cast<bf16x8_t*>(hh); \
                *reinterpret_cast<bf16x8_t*>(&Bsl[buf][blk * 8]) = *reinterpret_cast<bf16x8_t*>(ll); \
            } else {                                                                            \
                *reinterpret_cast<bf16x8_t*>(&Bsh[buf][blk * 8]) = rBh_[j];                     \
                *reinterpret_cast<bf16x8_t*>(&Bsl[buf][blk * 8]) = rBl_[j];                     \
            }                                                                                   \
        }                                                                                       \
    }

    auto compute = [&](int buf) {
        bf16x8_t fah[4], fal[4], fbh[NF], fbl[NF];
        #pragma unroll
        for (int m = 0; m < 4; ++m) {
            int row = wm * 64 + m * 16 + fr;
            int blk = row * 4 + (kg ^ ((row >> 1) & 3));
            fah[m] = *reinterpret_cast<const bf16x8_t*>(&Ash[buf][blk * 8]);
            fal[m] = *reinterpret_cast<const bf16x8_t*>(&Asl[buf][blk * 8]);
        }
        #pragma unroll
        for (int n = 0; n < NF; ++n) {
            int row = wn * WC + n * 16 + fr;
            int blk = row * 4 + (kg ^ ((row >> 1) & 3));
            fbh[n] = *reinterpret_cast<const bf16x8_t*>(&Bsh[buf][blk * 8]);
            fbl[n] = *reinterpret_cast<const bf16x8_t*>(&Bsl[buf][blk * 8]);
        }
        #pragma unroll
        for (int m = 0; m < 4; ++m)
            #pragma unroll
            for (int n = 0; n < NF; ++n) {
                acc[m][n] = __builtin_amdgcn_mfma_f32_16x16x32_bf16(fah[m], fbh[n], acc[m][n], 0, 0, 0);
                acc[m][n] = __builtin_amdgcn_mfma_f32_16x16x32_bf16(fah[m], fbl[n], acc[m][n], 0, 0, 0);
                acc[m][n] = __builtin_amdgcn_mfma_f32_16x16x32_bf16(fal[m], fbh[n], acc[m][n], 0, 0, 0);
            }
    };

    if constexpr (DBUF) {
        // depth-1 double-buffer (round-7/8 proven path), set 0 only
        LOAD_TILE(0, rAh0, rAl0, rAf0, rBh0, rBl0, rBf0);
        WRITE_TILE(0, rAh0, rAl0, rAf0, rBh0, rBl0, rBf0);
        __syncthreads();
        int cur = 0;
        for (int k0 = 0; k0 < K; k0 += 32) {
            const bool has_next = (k0 + 32) < K;
            if (has_next) LOAD_TILE(k0 + 32, rAh0, rAl0, rAf0, rBh0, rBl0, rBf0);
            compute(cur);
            if (has_next) {
                if (cur) { WRITE_TILE(0, rAh0, rAl0, rAf0, rBh0, rBl0, rBf0); }
                else     { WRITE_TILE(1, rAh0, rAl0, rAf0, rBh0, rBl0, rBf0); }
                __syncthreads();
                cur ^= 1;
            }
        }
    } else {
        // depth-2 single-buffer: tile t staged via reg set (t&1)
        const int nk = K >> 5;
        LOAD_TILE(0, rAh0, rAl0, rAf0, rBh0, rBl0, rBf0);
        WRITE_TILE(0, rAh0, rAl0, rAf0, rBh0, rBl0, rBf0);
        if (nk > 1) LOAD_TILE(32, rAh1, rAl1, rAf1, rBh1, rBl1, rBf1);
        __syncthreads();
        int i = 0;
        while (true) {
            // tile i (even parity)
            if (i + 2 < nk) LOAD_TILE((i + 2) << 5, rAh0, rAl0, rAf0, rBh0, rBl0, rBf0);
            compute(0);
            if (i + 1 >= nk) break;
            __syncthreads();
            WRITE_TILE(0, rAh1, rAl1, rAf1, rBh1, rBl1, rBf1);   // tile i+1
            __syncthreads();
            // tile i+1 (odd parity)
            if (i + 3 < nk) LOAD_TILE((i + 3) << 5, rAh1, rAl1, rAf1, rBh1, rBl1, rBf1);
            compute(0);
            if (i + 2 >= nk) break;
            __syncthreads();
            WRITE_TILE(0, rAh0, rAl0, rAf0, rBh0, rBl0, rBf0);   // tile i+2
            __syncthreads();
            i += 2;
        }
    }
#undef LOAD_TILE
#undef WRITE_TILE

    const int fq = lane >> 4;
    const float* bp_ = bias + (long long)biasStride * z;

    if constexpr (OUT == 2) {
        float psum[4][4] = {};
        #pragma unroll
        for (int n = 0; n < NF; ++n) {
            int col = bn + wn * WC + n * 16 + fr;
            float bv = bp_[col];
            float wv = w3[(long long)biasStride * z + col];
            #pragma unroll
            for (int m = 0; m < 4; ++m)
                #pragma unroll
                for (int r = 0; r < 4; ++r) {
                    float v = acc[m][n][r] + bv;
                    v = gelu_f(v);
                    psum[m][r] += v * wv;
                }
        }
        #pragma unroll
        for (int m = 0; m < 4; ++m)
            #pragma unroll
            for (int r = 0; r < 4; ++r) {
                float p = psum[m][r];
                p += __shfl_xor(p, 1);
                p += __shfl_xor(p, 2);
                p += __shfl_xor(p, 4);
                p += __shfl_xor(p, 8);
                if (fr == 0) {
                    int row = bm + wm * 64 + m * 16 + fq * 4 + r;
                    atomicAdd(&lg[czS * z + row], p);
                }
            }
        return;
    }

    #pragma unroll
    for (int n = 0; n < NF; ++n) {
        int col = bn + wn * WC + n * 16 + fr;
        float bv = bp_[col];
        #pragma unroll
        for (int m = 0; m < 4; ++m) {
            int row0 = bm + wm * 64 + m * 16 + fq * 4;
            #pragma unroll
            for (int r = 0; r < 4; ++r) {
                float v = acc[m][n][r] + bv;
                if (ACT == 1) v = gelu_f(v);
                long long ci = czS * z + (long long)(row0 + r) * ldc + col;
                if constexpr (OUT == 0) {
                    Cf[ci] = v;
                } else {
                    __hip_bfloat16 hh, ll;
                    split2(v, hh, ll);
                    Ch[ci] = hh; Cl[ci] = ll;
                }
            }
        }
    }
}

// ---------------- bf16 MFMA GEMM (continuous path), dbuf single-barrier ------
template<int ACT, int OUT_BF16>
__global__ __launch_bounds__(256)
void mfma_gemm(const __hip_bfloat16* __restrict__ A, const __hip_bfloat16* __restrict__ Bw,
               const float* __restrict__ bias, void* __restrict__ Cout,
               int M, int N, int K)
{
    __shared__ __align__(16) __hip_bfloat16 As[2][128 * 32];
    __shared__ __align__(16) __hip_bfloat16 Bs[2][128 * 32];
    const int tid = threadIdx.x;
    const int lane = tid & 63;
    const int wave = tid >> 6;
    const int wm = wave >> 1, wn = wave & 1;
    int bxi = blockIdx.x, byi = blockIdx.y;
    xcd_swizzle(bxi, byi, gridDim.x, gridDim.y);
    const int bm = byi * 128, bn = bxi * 128;
    const int srow = tid >> 2;
    const int skg = tid & 3;
    const int fr = lane & 15, kg = lane >> 4;

    f32x4_t acc[4][4] = {};
    bf16x8_t rA[2], rB[2];

    auto load_tile = [&](int k0) {
        #pragma unroll
        for (int it = 0; it < 2; ++it) {
            int r = srow + it * 64;
            rA[it] = *reinterpret_cast<const bf16x8_t*>(&A[(long long)(bm + r) * K + k0 + skg * 8]);
            rB[it] = *reinterpret_cast<const bf16x8_t*>(&Bw[(long long)(bn + r) * K + k0 + skg * 8]);
        }
    };
    auto write_tile = [&](int buf) {
        #pragma unroll
        for (int it = 0; it < 2; ++it) {
            int r = srow + it * 64;
            int blk = r * 4 + (skg ^ ((r >> 1) & 3));
            *reinterpret_cast<bf16x8_t*>(&As[buf][blk * 8]) = rA[it];
            *reinterpret_cast<bf16x8_t*>(&Bs[buf][blk * 8]) = rB[it];
        }
    };

    load_tile(0);
    write_tile(0);
    __syncthreads();
    int cur = 0;

    for (int k0 = 0; k0 < K; k0 += 32) {
        const bool has_next = (k0 + 32) < K;
        if (has_next) load_tile(k0 + 32);

        bf16x8_t af[4], bfr[4];
        #pragma unroll
        for (int m = 0; m < 4; ++m) {
            int row = wm * 64 + m * 16 + fr;
            af[m] = *reinterpret_cast<const bf16x8_t*>(&As[cur][(row * 4 + (kg ^ ((row >> 1) & 3))) * 8]);
        }
        #pragma unroll
        for (int n = 0; n < 4; ++n) {
            int row = wn * 64 + n * 16 + fr;
            bfr[n] = *reinterpret_cast<const bf16x8_t*>(&Bs[cur][(row * 4 + (kg ^ ((row >> 1) & 3))) * 8]);
        }
        #pragma unroll
        for (int m = 0; m < 4; ++m)
            #pragma unroll
            for (int n = 0; n < 4; ++n)
                acc[m][n] = __builtin_amdgcn_mfma_f32_16x16x32_bf16(af[m], bfr[n], acc[m][n], 0, 0, 0);

        if (has_next) {
            write_tile(cur ^ 1);
            __syncthreads();
            cur ^= 1;
        }
    }
    const int fq = lane >> 4;
    #pragma unroll
    for (int n = 0; n < 4; ++n) {
        int col = bn + wn * 64 + n * 16 + fr;
        float bv = bias[col];
        #pragma unroll
        for (int m = 0; m < 4; ++m) {
            int row0 = bm + wm * 64 + m * 16 + fq * 4;
            #pragma unroll
            for (int r = 0; r < 4; ++r) {
                float v = acc[m][n][r] + bv;
                if (ACT == 1) v = gelu_f(v);
                if (OUT_BF16) ((__hip_bfloat16*)Cout)[(long long)(row0 + r) * N + col] = __float2bfloat16(v);
                else          ((float*)Cout)[(long long)(row0 + r) * N + col] = v;
            }
        }
    }
}

// ---------------- conversion kernels -----------------------------------------
__global__ __launch_bounds__(256)
void f2b_kernel(const float* __restrict__ in, __hip_bfloat16* __restrict__ out, int n4)
{
    int i = blockIdx.x * 256 + threadIdx.x;
    if (i >= n4) return;
    float4 v = reinterpret_cast<const float4*>(in)[i];
    __hip_bfloat16 h[4] = { __float2bfloat16(v.x), __float2bfloat16(v.y),
                            __float2bfloat16(v.z), __float2bfloat16(v.w) };
    reinterpret_cast<short4*>(out)[i] = *reinterpret_cast<short4*>(h);
}

__global__ __launch_bounds__(256)
void split_kernel(const float* __restrict__ in, __hip_bfloat16* __restrict__ oh,
                  __hip_bfloat16* __restrict__ ol, int n4)
{
    int i = blockIdx.x * 256 + threadIdx.x;
    if (i >= n4) return;
    float4 v = reinterpret_cast<const float4*>(in)[i];
    __hip_bfloat16 h[4], l[4];
    split2(v.x, h[0], l[0]); split2(v.y, h[1], l[1]);
    split2(v.z, h[2], l[2]); split2(v.w, h[3], l[3]);
    reinterpret_cast<short4*>(oh)[i] = *reinterpret_cast<short4*>(h);
    reinterpret_cast<short4*>(ol)[i] = *reinterpret_cast<short4*>(l);
}

// ---------------- boundary-path small kernels --------------------------------
__global__ __launch_bounds__(64)
void cs_kernel(const float* __restrict__ xl, float* __restrict__ cs)
{
    int idx = blockIdx.x;
    int b = blockIdx.y;
    int sc, i, off;
    if (idx < 1023)      { sc = 1; i = idx;        off = 0;    }
    else if (idx < 1534) { sc = 2; i = idx - 1023; off = 1023; }
    else                 { sc = 4; i = idx - 1534; off = 1534; }
    const float* ra = xl + ((long long)b * S_ + (long long)i * sc) * D_;
    const float* rb = ra + (long long)sc * D_;
    int lane = threadIdx.x;
    float dp = 0.f, na = 0.f, nb = 0.f;
    for (int d = lane; d < D_; d += 64) {
        float a = ra[d], c = rb[d];
        dp += a * c; na += a * a; nb += c * c;
    }
    #pragma unroll
    for (int o = 32; o; o >>= 1) {
        dp += __shfl_down(dp, o);
        na += __shfl_down(na, o);
        nb += __shfl_down(nb, o);
    }
    if (lane == 0) {
        float den = fmaxf(sqrtf(na), 1e-8f) * fmaxf(sqrtf(nb), 1e-8f);
        cs[(long long)b * 1789 + off + i] = dp / den;
    }
}

__global__ void final_kernel(const float* __restrict__ cs, const float* __restrict__ logits,
                             const float* __restrict__ b3, float* __restrict__ fin)
{
    int g = blockIdx.x * blockDim.x + threadIdx.x;
    if (g >= B_ * 1023) return;
    int b = g / 1023, t = g % 1023;
    const float* c = cs + (long long)b * 1789;
    float v0 = c[t];
    const float r2 = (float)(511.0 / 1023.0);
    float src2 = fminf(fmaxf(((float)t + 0.5f) * r2 - 0.5f, 0.0f), 510.0f);
    int i0 = (int)floorf(src2);
    int i1 = min(i0 + 1, 510);
    float w2 = src2 - (float)i0;
    float v1 = c[1023 + i0] * (1.0f - w2) + c[1023 + i1] * w2;
    const float r4 = (float)(255.0 / 1023.0);
    float src4 = fminf(fmaxf(((float)t + 0.5f) * r4 - 0.5f, 0.0f), 254.0f);
    int j0 = (int)floorf(src4);
    int j1 = min(j0 + 1, 254);
    float w4 = src4 - (float)j0;
    float v2 = c[1534 + j0] * (1.0f - w4) + c[1534 + j1] * w4;
    float avg = ((v0 + v1) + v2) / 3.0f;
    float base = 0.5f * (1.0f - avg);
    int rr = b * 1024 + t;
    float l0 = 1.0f / (1.0f + expf(-(logits[0 * 4096 + rr] + b3[0])));
    float l1 = 1.0f / (1.0f + expf(-(logits[1 * 4096 + rr] + b3[1])));
    float l2 = 1.0f / (1.0f + expf(-(logits[2 * 4096 + rr] + b3[2])));
    float al = ((l0 + l1) + l2) / 3.0f;
    fin[g] = 0.6f * base + 0.4f * al;
}

// 64-lane scan cumsum of boundary bits
__global__ __launch_bounds__(64)
void seg_kernel(const float* __restrict__ fin, int* __restrict__ seg)
{
    int b = blockIdx.x;
    int lane = threadIdx.x;
    int loc[16];
    int cnt = 0;
    #pragma unroll
    for (int i = 0; i < 16; ++i) {
        int t = lane * 16 + i;
        int v = (t >= 1 && fin[b * 1023 + t - 1] > 0.5f) ? 1 : 0;
        cnt += v;
        loc[i] = cnt;
    }
    int inc = cnt;
    #pragma unroll
    for (int o = 1; o < 64; o <<= 1) {
        int u = __shfl_up(inc, o);
        if (lane >= o) inc += u;
    }
    int ex = inc - cnt;
    #pragma unroll
    for (int i = 0; i < 16; ++i) {
        int t = lane * 16 + i;
        seg[b * S_ + t] = ex + loc[i];
    }
}

__global__ void segrange_kernel(const float* __restrict__ fin, const int* __restrict__ seg,
                                int* __restrict__ sstart, int* __restrict__ send,
                                int* __restrict__ cfirst, int* __restrict__ ccount)
{
    int gs = blockIdx.x * blockDim.x + threadIdx.x;
    if (gs >= B_ * S_) return;
    int b = gs / S_, s = gs % S_;
    const float* f = fin + b * 1023;
    int t = s;
    while (t > 0 && !(f[t - 1] > 0.5f)) --t;
    int e = s;
    while (e < 1023 && !(f[e] > 0.5f)) ++e;
    sstart[gs] = t;
    send[gs] = e + 1;
    if (s == t) {
        int m = seg[gs];
        if (m < MAXC_) { cfirst[b * MAXC_ + m] = t; ccount[b * MAXC_ + m] = e + 1 - t; }
    }
}

// 4 heads per block: block=(64,4), grid=(4096,3); each y-wave owns one head.
__global__ __launch_bounds__(256)
void attn_kernel(const __hip_bfloat16* __restrict__ qkv, const int* __restrict__ sstart,
                 const int* __restrict__ send, __hip_bfloat16* __restrict__ ctx)
{
    int gs = blockIdx.x;
    int h = blockIdx.y * 4 + threadIdx.y;
    int lane = threadIdx.x;
    int b = gs >> 10;
    const __hip_bfloat16* qrow = qkv + (long long)gs * 4608 + h * HD_;
    float q0 = __bfloat162float(qrow[lane]), q1 = __bfloat162float(qrow[lane + 64]);
    int st = sstart[gs], en = send[gs];
    float m = -INFINITY, l = 0.f, a0 = 0.f, a1 = 0.f;
    for (int t = st; t < en; ++t) {
        long long krow = ((long long)(b * S_ + t)) * 4608 + 1536 + h * HD_;
        float p = q0 * __bfloat162float(qkv[krow + lane]) + q1 * __bfloat162float(qkv[krow + lane + 64]);
        #pragma unroll
        for (int o = 32; o; o >>= 1) p += __shfl_xor(p, o);
        p = p / 11.3137084989847603904f;
        float nm = fmaxf(m, p);
        float scale = expf(m - nm);
        float w = expf(p - nm);
        long long vrow = ((long long)(b * S_ + t)) * 4608 + 3072 + h * HD_;
        l = l * scale + w;
        a0 = a0 * scale + w * __bfloat162float(qkv[vrow + lane]);
        a1 = a1 * scale + w * __bfloat162float(qkv[vrow + lane + 64]);
        m = nm;
    }
    float inv = 1.0f / l;
    ctx[(long long)gs * D_ + h * HD_ + lane] = __float2bfloat16(a0 * inv);
    ctx[(long long)gs * D_ + h * HD_ + lane + 64] = __float2bfloat16(a1 * inv);
}

__global__ __launch_bounds__(256)
void chunk_kernel(const float* __restrict__ attn_out, const int* __restrict__ cfirst,
                  const int* __restrict__ ccount, const float* __restrict__ size_emb,
                  const float* __restrict__ pos_enc, __hip_bfloat16* __restrict__ chunk)
{
    int m = blockIdx.x, b = blockIdx.y;
    int cnt = ccount[b * MAXC_ + m];
    for (int d = threadIdx.x; d < D_; d += 256) {
        float v;
        if (cnt > 0) {
            int first = cfirst[b * MAXC_ + m];
            float ssum = 0.f;
            for (int t = 0; t < cnt; ++t)
                ssum += attn_out[((long long)(b * S_ + first + t)) * D_ + d];
            float mean = ssum / (float)cnt;
            int clen = min(cnt, 1023);
            v = mean + size_emb[(long long)clen * D_ + d];
        } else {
            v = 0.f;
        }
        v += pos_enc[m * D_ + d];
        chunk[((long long)(b * MAXC_ + m)) * D_ + d] = __float2bfloat16(v);
    }
}

__global__ __launch_bounds__(256)
void ln_kernel(const float* __restrict__ y0, const float* __restrict__ g,
               const float* __restrict__ bb, float* __restrict__ out)
{
    int r = blockIdx.x;
    const float* row = y0 + (long long)r * D_;
    float loc[6];
    float s = 0.f;
    #pragma unroll
    for (int i = 0; i < 6; ++i) { loc[i] = row[threadIdx.x + i * 256]; s += loc[i]; }
    __shared__ float red[256];
    red[threadIdx.x] = s; __syncthreads();
    for (int o = 128; o; o >>= 1) { if (threadIdx.x < o) red[threadIdx.x] += red[threadIdx.x + o]; __syncthreads(); }
    float mu = red[0] / 1536.0f;
    __syncthreads();
    float s2 = 0.f;
    #pragma unroll
    for (int i = 0; i < 6; ++i) { float d = loc[i] - mu; s2 += d * d; }
    red[threadIdx.x] = s2; __syncthreads();
    for (int o = 128; o; o >>= 1) { if (threadIdx.x < o) red[threadIdx.x] += red[threadIdx.x + o]; __syncthreads(); }
    float var = red[0] / 1536.0f;
    float inv = 1.0f / sqrtf(var + 1e-5f);
    #pragma unroll
    for (int i = 0; i < 6; ++i) {
        int d = threadIdx.x + i * 256;
        out[(long long)r * D_ + d] = (loc[i] - mu) * inv * g[d] + bb[d];
    }
}

extern "C" void kernel_launch(void* const* d_in, const int* in_sizes, int n_in,
                              void* d_out, int out_size, void* d_ws, size_t ws_size,
                              hipStream_t stream)
{
    const float* x         = (const float*)d_in[0];
    const float* Wp        = (const float*)d_in[1];
    const float* bp        = (const float*)d_in[2];
    const float* detW1     = (const float*)d_in[3];
    const float* detb1     = (const float*)d_in[4];
    const float* detW2     = (const float*)d_in[5];
    const float* detb2     = (const float*)d_in[6];
    const float* detW3     = (const float*)d_in[7];
    const float* detb3     = (const float*)d_in[8];
    const float* in_proj_w = (const float*)d_in[9];
    const float* in_proj_b = (const float*)d_in[10];
    const float* out_w     = (const float*)d_in[11];
    const float* out_b     = (const float*)d_in[12];
    const float* size_emb  = (const float*)d_in[13];
    const float* pos_enc   = (const float*)d_in[14];
    const float* procW1    = (const float*)d_in[15];
    const float* procb1    = (const float*)d_in[16];
    const float* procW2    = (const float*)d_in[17];
    const float* procb2    = (const float*)d_in[18];
    const float* ln_g      = (const float*)d_in[19];
    const float* ln_b      = (const float*)d_in[20];
    float* out = (float*)d_out;

    const bool big = ws_size >= (size_t)192 * 1024 * 1024;

    char* ws = (char*)d_ws;
    // --- common det-phase ---
    float*          xlingf = (float*)(ws + 0);                  // 25.17 MB, dead after cs
    __hip_bfloat16* Wph    = (__hip_bfloat16*)(ws + 25165824);  // 4.72 MB
    __hip_bfloat16* Wpl    = (__hip_bfloat16*)(ws + 29884416);  // 4.72 MB
    __hip_bfloat16* h1h    = (__hip_bfloat16*)(ws + 0);         // 37.75 MB (after cs)
    __hip_bfloat16* h1l    = (__hip_bfloat16*)(ws + 37748736);  // 37.75 MB
    // --- small path ---
    __hip_bfloat16* W1h_s  = (__hip_bfloat16*)(ws + 75497472);  // 18.87 MB (2 slices)
    __hip_bfloat16* W1l_s  = (__hip_bfloat16*)(ws + 94371840);  // 18.87 MB
    __hip_bfloat16* W2h_s  = (__hip_bfloat16*)(ws + 75497472);  // 7.08 MB (after h1)
    __hip_bfloat16* W2l_s  = (__hip_bfloat16*)(ws + 82575360);  // 7.08 MB
    // --- big path ---
    __hip_bfloat16* xh     = (__hip_bfloat16*)(ws + 75497472);  // 12.58 MB
    __hip_bfloat16* xl     = (__hip_bfloat16*)(ws + 88082432);  // 12.58 MB
    __hip_bfloat16* W1h_b  = (__hip_bfloat16*)(ws + 125829120); // 28.31 MB (3 slices)
    __hip_bfloat16* W1l_b  = (__hip_bfloat16*)(ws + 154140672); // 28.31 MB
    __hip_bfloat16* W2h_b  = (__hip_bfloat16*)(ws + 125829120); // 7.08 MB (after h1)
    __hip_bfloat16* W2l_b  = (__hip_bfloat16*)(ws + 132907008); // 7.08 MB
    // --- continuous phase ---
    __hip_bfloat16* xb_s       = (__hip_bfloat16*)(ws + 0);
    __hip_bfloat16* in_proj_wb = (__hip_bfloat16*)(ws + 12582912);
    __hip_bfloat16* qkvb       = (__hip_bfloat16*)(ws + 26738688);
    __hip_bfloat16* ctxb       = (__hip_bfloat16*)(ws + 64487424);
    __hip_bfloat16* out_wb     = (__hip_bfloat16*)(ws + 12582912);
    float*          attno      = (float*)(ws + 77070336);
    __hip_bfloat16* chunkb     = (__hip_bfloat16*)(ws + 0);
    __hip_bfloat16* procW1b    = (__hip_bfloat16*)(ws + 3145728);
    __hip_bfloat16* hmidb      = (__hip_bfloat16*)(ws + 12582912);
    __hip_bfloat16* procW2b    = (__hip_bfloat16*)(ws + 18874368);
    float*          y0         = (float*)(ws + 28311552);
    // --- small persistent ---
    char* sm = ws + 113246208;
    float* csb    = (float*)(sm + 0);
    float* logits = (float*)(sm + 28672);
    float* fin    = (float*)(sm + 77824);
    int*   seg    = (int*)  (sm + 94208);
    int*   sstart = (int*)  (sm + 110592);
    int*   send   = (int*)  (sm + 126976);
    int*   cfirst = (int*)  (sm + 143360);
    int*   ccount = (int*)  (sm + 147456);

    const long long SLICE_W1 = 4718592LL;   // 1536*3072
    const long long SLICE_W2 = 1179648LL;   // 768*1536
    const long long H1_Z     = 6291456LL;   // 4096*1536

    // 0) pre-splits
    split_kernel<<<(2359296 / 4 + 255) / 256, 256, 0, stream>>>(Wp, Wph, Wpl, 2359296 / 4);
    if (big)
        split_kernel<<<(6291456 / 4 + 255) / 256, 256, 0, stream>>>(x, xh, xl, 6291456 / 4);

    // 1) x_ling via split-bf16 MFMA + cosine sims (DBUF=1: small grid / short K)
    if (big)
        mfma3_gemm<128, 0, 0, 0, 0, 1><<<dim3(12, 32, 1), 256, 0, stream>>>(
            nullptr, xh, xl, nullptr, Wph, Wpl, bp, 0,
            xlingf, nullptr, nullptr, nullptr, nullptr,
            1536, 1536, 1536, 1536, 0LL, 0LL, 0LL, 0LL);
    else
        mfma3_gemm<64, 1, 0, 0, 0, 1><<<dim3(12, 64, 1), 256, 0, stream>>>(
            x, nullptr, nullptr, nullptr, Wph, Wpl, bp, 0,
            xlingf, nullptr, nullptr, nullptr, nullptr,
            1536, 1536, 1536, 1536, 6291456LL, 0LL, 0LL, 0LL);
    cs_kernel<<<dim3(1789, 4), 64, 0, stream>>>(xlingf, csb);

    // 2) detector h1 (DBUF=0 + depth-2 register prefetch)
    if (big) {
        split_kernel<<<(14155776 / 4 + 255) / 256, 256, 0, stream>>>(detW1, W1h_b, W1l_b, 14155776 / 4);
        mfma3_gemm<128, 0, 0, 1, 1, 0><<<dim3(12, 32, 3), 256, 0, stream>>>(
            nullptr, xh, xl, nullptr, W1h_b, W1l_b, detb1, 1536,
            nullptr, h1h, h1l, nullptr, nullptr,
            3072, 1536, 3072, 1536, 0LL, 0LL, SLICE_W1, H1_Z);
    } else {
        split_kernel<<<(2 * 4718592 / 4 + 255) / 256, 256, 0, stream>>>(detW1, W1h_s, W1l_s, 2 * 4718592 / 4);
        mfma3_gemm<128, 1, 0, 1, 1, 0><<<dim3(12, 32, 2), 256, 0, stream>>>(
            x, nullptr, nullptr, nullptr, W1h_s, W1l_s, detb1, 1536,
            nullptr, h1h, h1l, nullptr, nullptr,
            3072, 1536, 3072, 1536, 6291456LL, 0LL, SLICE_W1, H1_Z);
        split_kernel<<<(4718592 / 4 + 255) / 256, 256, 0, stream>>>(detW1 + 2 * SLICE_W1, W1h_s, W1l_s, 4718592 / 4);
        mfma3_gemm<64, 1, 0, 1, 1, 0><<<dim3(12, 64, 1), 256, 0, stream>>>(
            x, nullptr, nullptr, nullptr, W1h_s, W1l_s, detb1 + 2 * 1536, 1536,
            nullptr, h1h + 2 * H1_Z, h1l + 2 * H1_Z, nullptr, nullptr,
            3072, 1536, 3072, 1536, 6291456LL, 0LL, 0LL, 0LL);
    }

    // 3) detector h2 + fused logit dot (DBUF=1)
    __hip_bfloat16* W2h = big ? W2h_b : W2h_s;
    __hip_bfloat16* W2l = big ? W2l_b : W2l_s;
    split_kernel<<<(3538944 / 4 + 255) / 256, 256, 0, stream>>>(detW2, W2h, W2l, 3538944 / 4);
    hipMemsetAsync(logits, 0, 3 * 4096 * sizeof(float), stream);
    mfma3_gemm<128, 0, 0, 1, 2, 1><<<dim3(6, 32, 3), 256, 0, stream>>>(
        nullptr, h1h, h1l, nullptr, W2h, W2l, detb2, 768,
        nullptr, nullptr, nullptr, detW3, logits,
        1536, 1536, 1536, 768, 0LL, H1_Z, SLICE_W2, 4096LL);

    // 4) boundaries + segments
    final_kernel<<<16, 256, 0, stream>>>(csb, logits, detb3, fin);
    seg_kernel<<<4, 64, 0, stream>>>(fin, seg);
    hipMemsetAsync(ccount, 0, B_ * MAXC_ * sizeof(int), stream);
    segrange_kernel<<<16, 256, 0, stream>>>(fin, seg, sstart, send, cfirst, ccount);

    // 5) qkv projection (bf16 MFMA)
    const __hip_bfloat16* xbf;
    if (big) {
        xbf = xh;  // identical to f2b(x)
    } else {
        f2b_kernel<<<(4096 * 1536 / 4 + 255) / 256, 256, 0, stream>>>(x, xb_s, 4096 * 1536 / 4);
        xbf = xb_s;
    }
    f2b_kernel<<<(4608 * 1536 / 4 + 255) / 256, 256, 0, stream>>>(in_proj_w, in_proj_wb, 4608 * 1536 / 4);
    mfma_gemm<0, 1><<<dim3(36, 32), 256, 0, stream>>>(xbf, in_proj_wb, in_proj_b, qkvb, 4096, 4608, 1536);

    // 6) block-diagonal attention (4 heads per block)
    attn_kernel<<<dim3(4096, 3), dim3(64, 4), 0, stream>>>(qkvb, sstart, send, ctxb);

    // 7) output projection
    f2b_kernel<<<(1536 * 1536 / 4 + 255) / 256, 256, 0, stream>>>(out_w, out_wb, 1536 * 1536 / 4);
    mfma_gemm<0, 0><<<dim3(12, 32), 256, 0, stream>>>(ctxb, out_wb, out_b, attno, 4096, 1536, 1536);

    // 8) chunk means + size emb + pos enc
    chunk_kernel<<<dim3(256, 4), 256, 0, stream>>>(attno, cfirst, ccount, size_emb, pos_enc, chunkb);

    // 9) chunk MLP
    f2b_kernel<<<(3072 * 1536 / 4 + 255) / 256, 256, 0, stream>>>(procW1, procW1b, 3072 * 1536 / 4);
    mfma_gemm<1, 1><<<dim3(24, 8), 256, 0, stream>>>(chunkb, procW1b, procb1, hmidb, 1024, 3072, 1536);
    f2b_kernel<<<(1536 * 3072 / 4 + 255) / 256, 256, 0, stream>>>(procW2, procW2b, 1536 * 3072 / 4);
    mfma_gemm<0, 0><<<dim3(12, 8), 256, 0, stream>>>(hmidb, procW2b, procb2, y0, 1024, 1536, 3072);

    // 10) layernorm -> output
    ln_kernel<<<1024, 256, 0, stream>>>(y0, ln_g, ln_b, out);
}

// Round 10
// 1043.713 us; speedup vs baseline: 1.1105x; 1.1105x over previous
//
#include <hip/hip_runtime.h>
#include <hip/hip_bf16.h>
#include <math.h>

#define D_ 1536
#define S_ 1024
#define B_ 4
#define H_ 12
#define HD_ 128
#define MAXC_ 256

typedef __bf16 bf16x8_t __attribute__((ext_vector_type(8)));
typedef float f32x4_t __attribute__((ext_vector_type(4)));

__device__ __forceinline__ float gelu_f(float v) {
    return 0.5f * v * (1.0f + erff(v / 1.41421356237f));
}

__device__ __forceinline__ void split2(float a, __hip_bfloat16& h, __hip_bfloat16& l) {
    h = __float2bfloat16(a);
    l = __float2bfloat16(a - __bfloat162float(h));
}

// bijective XCD swizzle (m204)
__device__ __forceinline__ void xcd_swizzle(int& bx, int& by, int gx, int gy) {
    int nwg = gx * gy;
    int orig = by * gx + bx;
    int xcd = orig & 7;
    int q = nwg >> 3, r = nwg & 7;
    int wg = (xcd < r ? xcd * (q + 1) : r * (q + 1) + (xcd - r) * q) + (orig >> 3);
    bx = wg % gx;
    by = wg / gx;
}

// ---------------- split-bf16 MFMA GEMM (BM=128/64) — ROUND-8 PROVEN ----------
// acc += Ah*Bh + Ah*Bl + Al*Bh; K-step 32; T14 prefetch (load k+1 before MFMAs).
// DBUF=0: single LDS buffer, 2 barriers/K-step (proven best for long-K h1).
// DBUF=1: double buffer, 1 barrier/K-step (better for short-K / small grids).
// OUT: 0 = fp32 C, 1 = bf16 split-pair C, 2 = gelu + dot(w3) -> atomicAdd(lg)
template<int BM, int SPLITA, int SPLITB, int ACT, int OUT, int DBUF>
__global__ __launch_bounds__(256, 2)
void mfma3_gemm(const float* __restrict__ Af, const __hip_bfloat16* __restrict__ Ah,
                const __hip_bfloat16* __restrict__ Al,
                const float* __restrict__ Bf, const __hip_bfloat16* __restrict__ Bh,
                const __hip_bfloat16* __restrict__ Bl,
                const float* __restrict__ bias, int biasStride,
                float* __restrict__ Cf, __hip_bfloat16* __restrict__ Ch, __hip_bfloat16* __restrict__ Cl,
                const float* __restrict__ w3, float* __restrict__ lg,
                int K, int lda, int ldb, int ldc,
                long long aBound, long long azS, long long bzS, long long czS)
{
    constexpr int NB = DBUF ? 2 : 1;
    __shared__ __align__(16) __hip_bfloat16 Ash[NB][BM * 32], Asl[NB][BM * 32];
    __shared__ __align__(16) __hip_bfloat16 Bsh[NB][128 * 32], Bsl[NB][128 * 32];
    const int z = blockIdx.z;
    int bxi = blockIdx.x, byi = blockIdx.y;
    xcd_swizzle(bxi, byi, gridDim.x, gridDim.y);
    const int bm = byi * BM, bn = bxi * 128;
    const int tid = threadIdx.x, lane = tid & 63, wave = tid >> 6;
    const int wm = (BM == 128) ? (wave >> 1) : 0;
    const int wn = (BM == 128) ? (wave & 1) : wave;
    constexpr int NF = (BM == 128) ? 4 : 2;
    constexpr int WC = NF * 16;
    const int fr = lane & 15, kg = lane >> 4;
    f32x4_t acc[4][NF] = {};
    constexpr int RSH = (BM == 128) ? 1 : 2;
    constexpr int NBA = (BM == 128) ? 2 : 1;
    const int ar = tid >> RSH, akb = tid & ((1 << RSH) - 1);
    const int br = tid >> 1, bkb = tid & 1;

    bf16x8_t rAh[NBA], rAl[NBA], rBh[2], rBl[2];
    float4 rAf[NBA][2], rBf[2][2];

    auto load_tile = [&](int k0) {
        #pragma unroll
        for (int j = 0; j < NBA; ++j) {
            int skg = akb * NBA + j;
            long long base = (long long)(bm + ar) * lda + azS * z + k0 + skg * 8;
            if (SPLITA) {
                #pragma unroll
                for (int q = 0; q < 2; ++q) {
                    float4 v = make_float4(0.f, 0.f, 0.f, 0.f);
                    if (base + q * 4 + 4 <= aBound) v = *reinterpret_cast<const float4*>(&Af[base + q * 4]);
                    rAf[j][q] = v;
                }
            } else {
                rAh[j] = *reinterpret_cast<const bf16x8_t*>(&Ah[base]);
                rAl[j] = *reinterpret_cast<const bf16x8_t*>(&Al[base]);
            }
        }
        #pragma unroll
        for (int j = 0; j < 2; ++j) {
            int skg = bkb * 2 + j;
            long long base = (long long)(bn + br) * ldb + bzS * z + k0 + skg * 8;
            if (SPLITB) {
                #pragma unroll
                for (int q = 0; q < 2; ++q)
                    rBf[j][q] = *reinterpret_cast<const float4*>(&Bf[base + q * 4]);
            } else {
                rBh[j] = *reinterpret_cast<const bf16x8_t*>(&Bh[base]);
                rBl[j] = *reinterpret_cast<const bf16x8_t*>(&Bl[base]);
            }
        }
    };

    auto write_tile = [&](int buf) {
        #pragma unroll
        for (int j = 0; j < NBA; ++j) {
            int skg = akb * NBA + j;
            int blk = ar * 4 + (skg ^ ((ar >> 1) & 3));
            if (SPLITA) {
                float av[8];
                *reinterpret_cast<float4*>(&av[0]) = rAf[j][0];
                *reinterpret_cast<float4*>(&av[4]) = rAf[j][1];
                __hip_bfloat16 hh[8], ll[8];
                #pragma unroll
                for (int q = 0; q < 8; ++q) split2(av[q], hh[q], ll[q]);
                *reinterpret_cast<bf16x8_t*>(&Ash[buf][blk * 8]) = *reinterpret_cast<bf16x8_t*>(hh);
                *reinterpret_cast<bf16x8_t*>(&Asl[buf][blk * 8]) = *reinterpret_cast<bf16x8_t*>(ll);
            } else {
                *reinterpret_cast<bf16x8_t*>(&Ash[buf][blk * 8]) = rAh[j];
                *reinterpret_cast<bf16x8_t*>(&Asl[buf][blk * 8]) = rAl[j];
            }
        }
        #pragma unroll
        for (int j = 0; j < 2; ++j) {
            int skg = bkb * 2 + j;
            int blk = br * 4 + (skg ^ ((br >> 1) & 3));
            if (SPLITB) {
                float av[8];
                *reinterpret_cast<float4*>(&av[0]) = rBf[j][0];
                *reinterpret_cast<float4*>(&av[4]) = rBf[j][1];
                __hip_bfloat16 hh[8], ll[8];
                #pragma unroll
                for (int q = 0; q < 8; ++q) split2(av[q], hh[q], ll[q]);
                *reinterpret_cast<bf16x8_t*>(&Bsh[buf][blk * 8]) = *reinterpret_cast<bf16x8_t*>(hh);
                *reinterpret_cast<bf16x8_t*>(&Bsl[buf][blk * 8]) = *reinterpret_cast<bf16x8_t*>(ll);
            } else {
                *reinterpret_cast<bf16x8_t*>(&Bsh[buf][blk * 8]) = rBh[j];
                *reinterpret_cast<bf16x8_t*>(&Bsl[buf][blk * 8]) = rBl[j];
            }
        }
    };

    load_tile(0);
    write_tile(0);
    __syncthreads();
    int cur = 0;

    for (int k0 = 0; k0 < K; k0 += 32) {
        const bool has_next = (k0 + 32) < K;
        if (has_next) load_tile(k0 + 32);   // issue early: latency hides under MFMAs

        bf16x8_t fah[4], fal[4], fbh[NF], fbl[NF];
        #pragma unroll
        for (int m = 0; m < 4; ++m) {
            int row = wm * 64 + m * 16 + fr;
            int blk = row * 4 + (kg ^ ((row >> 1) & 3));
            fah[m] = *reinterpret_cast<const bf16x8_t*>(&Ash[cur][blk * 8]);
            fal[m] = *reinterpret_cast<const bf16x8_t*>(&Asl[cur][blk * 8]);
        }
        #pragma unroll
        for (int n = 0; n < NF; ++n) {
            int row = wn * WC + n * 16 + fr;
            int blk = row * 4 + (kg ^ ((row >> 1) & 3));
            fbh[n] = *reinterpret_cast<const bf16x8_t*>(&Bsh[cur][blk * 8]);
            fbl[n] = *reinterpret_cast<const bf16x8_t*>(&Bsl[cur][blk * 8]);
        }
        #pragma unroll
        for (int m = 0; m < 4; ++m)
            #pragma unroll
            for (int n = 0; n < NF; ++n) {
                acc[m][n] = __builtin_amdgcn_mfma_f32_16x16x32_bf16(fah[m], fbh[n], acc[m][n], 0, 0, 0);
                acc[m][n] = __builtin_amdgcn_mfma_f32_16x16x32_bf16(fah[m], fbl[n], acc[m][n], 0, 0, 0);
                acc[m][n] = __builtin_amdgcn_mfma_f32_16x16x32_bf16(fal[m], fbh[n], acc[m][n], 0, 0, 0);
            }

        if (has_next) {
            if (DBUF) {
                write_tile(cur ^ 1);
                __syncthreads();
                cur ^= 1;
            } else {
                __syncthreads();   // all waves done reading this tile
                write_tile(0);     // loads landed during MFMAs
                __syncthreads();   // tile k+1 visible
            }
        }
    }

    const int fq = lane >> 4;
    const float* bp_ = bias + (long long)biasStride * z;

    if constexpr (OUT == 2) {
        float psum[4][4] = {};
        #pragma unroll
        for (int n = 0; n < NF; ++n) {
            int col = bn + wn * WC + n * 16 + fr;
            float bv = bp_[col];
            float wv = w3[(long long)biasStride * z + col];
            #pragma unroll
            for (int m = 0; m < 4; ++m)
                #pragma unroll
                for (int r = 0; r < 4; ++r) {
                    float v = acc[m][n][r] + bv;
                    v = gelu_f(v);
                    psum[m][r] += v * wv;
                }
        }
        #pragma unroll
        for (int m = 0; m < 4; ++m)
            #pragma unroll
            for (int r = 0; r < 4; ++r) {
                float p = psum[m][r];
                p += __shfl_xor(p, 1);
                p += __shfl_xor(p, 2);
                p += __shfl_xor(p, 4);
                p += __shfl_xor(p, 8);
                if (fr == 0) {
                    int row = bm + wm * 64 + m * 16 + fq * 4 + r;
                    atomicAdd(&lg[czS * z + row], p);
                }
            }
        return;
    }

    #pragma unroll
    for (int n = 0; n < NF; ++n) {
        int col = bn + wn * WC + n * 16 + fr;
        float bv = bp_[col];
        #pragma unroll
        for (int m = 0; m < 4; ++m) {
            int row0 = bm + wm * 64 + m * 16 + fq * 4;
            #pragma unroll
            for (int r = 0; r < 4; ++r) {
                float v = acc[m][n][r] + bv;
                if (ACT == 1) v = gelu_f(v);
                long long ci = czS * z + (long long)(row0 + r) * ldc + col;
                if constexpr (OUT == 0) {
                    Cf[ci] = v;
                } else {
                    __hip_bfloat16 hh, ll;
                    split2(v, hh, ll);
                    Ch[ci] = hh; Cl[ci] = ll;
                }
            }
        }
    }
}

// ---------------- bf16 MFMA GEMM (continuous path) — global_load_lds staging --
// Single 16KB LDS buffer, 2 barriers/K-step, direct global->LDS DMA (width 16).
// Swizzled layout achieved by pre-swizzling the per-lane GLOBAL source address
// (m173 pattern); LDS destination is linear (wave-uniform base + lane*16).
// Stored bytes identical to reg-staged version => bitwise-identical output.
template<int ACT, int OUT_BF16>
__global__ __launch_bounds__(256)
void mfma_gemm(const __hip_bfloat16* __restrict__ A, const __hip_bfloat16* __restrict__ Bw,
               const float* __restrict__ bias, void* __restrict__ Cout,
               int M, int N, int K)
{
    __shared__ __align__(16) __hip_bfloat16 As[128 * 32];
    __shared__ __align__(16) __hip_bfloat16 Bs[128 * 32];
    const int tid = threadIdx.x;
    const int lane = tid & 63;
    const int wave = tid >> 6;
    const int wm = wave >> 1, wn = wave & 1;
    int bxi = blockIdx.x, byi = blockIdx.y;
    xcd_swizzle(bxi, byi, gridDim.x, gridDim.y);
    const int bm = byi * 128, bn = bxi * 128;
    const int fr = lane & 15, kg = lane >> 4;

    f32x4_t acc[4][4] = {};

    // issue 4 global_load_lds per thread-slot: each wave fills 2 x 1KB chunks
    // of As and Bs. Chunk c covers 16B-blocks [(wave*2+c)*64, +64).
    auto stage = [&](int k0) {
        #pragma unroll
        for (int c = 0; c < 2; ++c) {
            int idx = (wave * 2 + c) * 64 + lane;     // 0..511 block index
            int row = idx >> 2, slot = idx & 3;
            int srck = slot ^ ((row >> 1) & 3);       // inverse swizzle on source
            const __hip_bfloat16* ga = &A[(long long)(bm + row) * K + k0 + srck * 8];
            const __hip_bfloat16* gb = &Bw[(long long)(bn + row) * K + k0 + srck * 8];
            __builtin_amdgcn_global_load_lds(
                (const __attribute__((address_space(1))) unsigned int*)ga,
                (__attribute__((address_space(3))) unsigned int*)&As[(wave * 2 + c) * 512],
                16, 0, 0);
            __builtin_amdgcn_global_load_lds(
                (const __attribute__((address_space(1))) unsigned int*)gb,
                (__attribute__((address_space(3))) unsigned int*)&Bs[(wave * 2 + c) * 512],
                16, 0, 0);
        }
    };

    for (int k0 = 0; k0 < K; k0 += 32) {
        stage(k0);
        __syncthreads();   // compiler drains vmcnt before barrier -> tile visible

        bf16x8_t af[4], bfr[4];
        #pragma unroll
        for (int m = 0; m < 4; ++m) {
            int row = wm * 64 + m * 16 + fr;
            af[m] = *reinterpret_cast<const bf16x8_t*>(&As[(row * 4 + (kg ^ ((row >> 1) & 3))) * 8]);
        }
        #pragma unroll
        for (int n = 0; n < 4; ++n) {
            int row = wn * 64 + n * 16 + fr;
            bfr[n] = *reinterpret_cast<const bf16x8_t*>(&Bs[(row * 4 + (kg ^ ((row >> 1) & 3))) * 8]);
        }
        #pragma unroll
        for (int m = 0; m < 4; ++m)
            #pragma unroll
            for (int n = 0; n < 4; ++n)
                acc[m][n] = __builtin_amdgcn_mfma_f32_16x16x32_bf16(af[m], bfr[n], acc[m][n], 0, 0, 0);

        __syncthreads();   // all waves done reading before next overwrite
    }
    const int fq = lane >> 4;
    #pragma unroll
    for (int n = 0; n < 4; ++n) {
        int col = bn + wn * 64 + n * 16 + fr;
        float bv = bias[col];
        #pragma unroll
        for (int m = 0; m < 4; ++m) {
            int row0 = bm + wm * 64 + m * 16 + fq * 4;
            #pragma unroll
            for (int r = 0; r < 4; ++r) {
                float v = acc[m][n][r] + bv;
                if (ACT == 1) v = gelu_f(v);
                if (OUT_BF16) ((__hip_bfloat16*)Cout)[(long long)(row0 + r) * N + col] = __float2bfloat16(v);
                else          ((float*)Cout)[(long long)(row0 + r) * N + col] = v;
            }
        }
    }
}

// ---------------- conversion kernels -----------------------------------------
__global__ __launch_bounds__(256)
void f2b_kernel(const float* __restrict__ in, __hip_bfloat16* __restrict__ out, int n4)
{
    int i = blockIdx.x * 256 + threadIdx.x;
    if (i >= n4) return;
    float4 v = reinterpret_cast<const float4*>(in)[i];
    __hip_bfloat16 h[4] = { __float2bfloat16(v.x), __float2bfloat16(v.y),
                            __float2bfloat16(v.z), __float2bfloat16(v.w) };
    reinterpret_cast<short4*>(out)[i] = *reinterpret_cast<short4*>(h);
}

__global__ __launch_bounds__(256)
void split_kernel(const float* __restrict__ in, __hip_bfloat16* __restrict__ oh,
                  __hip_bfloat16* __restrict__ ol, int n4)
{
    int i = blockIdx.x * 256 + threadIdx.x;
    if (i >= n4) return;
    float4 v = reinterpret_cast<const float4*>(in)[i];
    __hip_bfloat16 h[4], l[4];
    split2(v.x, h[0], l[0]); split2(v.y, h[1], l[1]);
    split2(v.z, h[2], l[2]); split2(v.w, h[3], l[3]);
    reinterpret_cast<short4*>(oh)[i] = *reinterpret_cast<short4*>(h);
    reinterpret_cast<short4*>(ol)[i] = *reinterpret_cast<short4*>(l);
}

// ---------------- boundary-path small kernels --------------------------------
__global__ __launch_bounds__(64)
void cs_kernel(const float* __restrict__ xl, float* __restrict__ cs)
{
    int idx = blockIdx.x;
    int b = blockIdx.y;
    int sc, i, off;
    if (idx < 1023)      { sc = 1; i = idx;        off = 0;    }
    else if (idx < 1534) { sc = 2; i = idx - 1023; off = 1023; }
    else                 { sc = 4; i = idx - 1534; off = 1534; }
    const float* ra = xl + ((long long)b * S_ + (long long)i * sc) * D_;
    const float* rb = ra + (long long)sc * D_;
    int lane = threadIdx.x;
    float dp = 0.f, na = 0.f, nb = 0.f;
    for (int d = lane; d < D_; d += 64) {
        float a = ra[d], c = rb[d];
        dp += a * c; na += a * a; nb += c * c;
    }
    #pragma unroll
    for (int o = 32; o; o >>= 1) {
        dp += __shfl_down(dp, o);
        na += __shfl_down(na, o);
        nb += __shfl_down(nb, o);
    }
    if (lane == 0) {
        float den = fmaxf(sqrtf(na), 1e-8f) * fmaxf(sqrtf(nb), 1e-8f);
        cs[(long long)b * 1789 + off + i] = dp / den;
    }
}

__global__ void final_kernel(const float* __restrict__ cs, const float* __restrict__ logits,
                             const float* __restrict__ b3, float* __restrict__ fin)
{
    int g = blockIdx.x * blockDim.x + threadIdx.x;
    if (g >= B_ * 1023) return;
    int b = g / 1023, t = g % 1023;
    const float* c = cs + (long long)b * 1789;
    float v0 = c[t];
    const float r2 = (float)(511.0 / 1023.0);
    float src2 = fminf(fmaxf(((float)t + 0.5f) * r2 - 0.5f, 0.0f), 510.0f);
    int i0 = (int)floorf(src2);
    int i1 = min(i0 + 1, 510);
    float w2 = src2 - (float)i0;
    float v1 = c[1023 + i0] * (1.0f - w2) + c[1023 + i1] * w2;
    const float r4 = (float)(255.0 / 1023.0);
    float src4 = fminf(fmaxf(((float)t + 0.5f) * r4 - 0.5f, 0.0f), 254.0f);
    int j0 = (int)floorf(src4);
    int j1 = min(j0 + 1, 254);
    float w4 = src4 - (float)j0;
    float v2 = c[1534 + j0] * (1.0f - w4) + c[1534 + j1] * w4;
    float avg = ((v0 + v1) + v2) / 3.0f;
    float base = 0.5f * (1.0f - avg);
    int rr = b * 1024 + t;
    float l0 = 1.0f / (1.0f + expf(-(logits[0 * 4096 + rr] + b3[0])));
    float l1 = 1.0f / (1.0f + expf(-(logits[1 * 4096 + rr] + b3[1])));
    float l2 = 1.0f / (1.0f + expf(-(logits[2 * 4096 + rr] + b3[2])));
    float al = ((l0 + l1) + l2) / 3.0f;
    fin[g] = 0.6f * base + 0.4f * al;
}

// 64-lane scan cumsum of boundary bits
__global__ __launch_bounds__(64)
void seg_kernel(const float* __restrict__ fin, int* __restrict__ seg)
{
    int b = blockIdx.x;
    int lane = threadIdx.x;
    int loc[16];
    int cnt = 0;
    #pragma unroll
    for (int i = 0; i < 16; ++i) {
        int t = lane * 16 + i;
        int v = (t >= 1 && fin[b * 1023 + t - 1] > 0.5f) ? 1 : 0;
        cnt += v;
        loc[i] = cnt;
    }
    int inc = cnt;
    #pragma unroll
    for (int o = 1; o < 64; o <<= 1) {
        int u = __shfl_up(inc, o);
        if (lane >= o) inc += u;
    }
    int ex = inc - cnt;
    #pragma unroll
    for (int i = 0; i < 16; ++i) {
        int t = lane * 16 + i;
        seg[b * S_ + t] = ex + loc[i];
    }
}

__global__ void segrange_kernel(const float* __restrict__ fin, const int* __restrict__ seg,
                                int* __restrict__ sstart, int* __restrict__ send,
                                int* __restrict__ cfirst, int* __restrict__ ccount)
{
    int gs = blockIdx.x * blockDim.x + threadIdx.x;
    if (gs >= B_ * S_) return;
    int b = gs / S_, s = gs % S_;
    const float* f = fin + b * 1023;
    int t = s;
    while (t > 0 && !(f[t - 1] > 0.5f)) --t;
    int e = s;
    while (e < 1023 && !(f[e] > 0.5f)) ++e;
    sstart[gs] = t;
    send[gs] = e + 1;
    if (s == t) {
        int m = seg[gs];
        if (m < MAXC_) { cfirst[b * MAXC_ + m] = t; ccount[b * MAXC_ + m] = e + 1 - t; }
    }
}

// 4 heads per block: block=(64,4), grid=(4096,3); each y-wave owns one head.
__global__ __launch_bounds__(256)
void attn_kernel(const __hip_bfloat16* __restrict__ qkv, const int* __restrict__ sstart,
                 const int* __restrict__ send, __hip_bfloat16* __restrict__ ctx)
{
    int gs = blockIdx.x;
    int h = blockIdx.y * 4 + threadIdx.y;
    int lane = threadIdx.x;
    int b = gs >> 10;
    const __hip_bfloat16* qrow = qkv + (long long)gs * 4608 + h * HD_;
    float q0 = __bfloat162float(qrow[lane]), q1 = __bfloat162float(qrow[lane + 64]);
    int st = sstart[gs], en = send[gs];
    float m = -INFINITY, l = 0.f, a0 = 0.f, a1 = 0.f;
    for (int t = st; t < en; ++t) {
        long long krow = ((long long)(b * S_ + t)) * 4608 + 1536 + h * HD_;
        float p = q0 * __bfloat162float(qkv[krow + lane]) + q1 * __bfloat162float(qkv[krow + lane + 64]);
        #pragma unroll
        for (int o = 32; o; o >>= 1) p += __shfl_xor(p, o);
        p = p / 11.3137084989847603904f;
        float nm = fmaxf(m, p);
        float scale = expf(m - nm);
        float w = expf(p - nm);
        long long vrow = ((long long)(b * S_ + t)) * 4608 + 3072 + h * HD_;
        l = l * scale + w;
        a0 = a0 * scale + w * __bfloat162float(qkv[vrow + lane]);
        a1 = a1 * scale + w * __bfloat162float(qkv[vrow + lane + 64]);
        m = nm;
    }
    float inv = 1.0f / l;
    ctx[(long long)gs * D_ + h * HD_ + lane] = __float2bfloat16(a0 * inv);
    ctx[(long long)gs * D_ + h * HD_ + lane + 64] = __float2bfloat16(a1 * inv);
}

__global__ __launch_bounds__(256)
void chunk_kernel(const float* __restrict__ attn_out, const int* __restrict__ cfirst,
                  const int* __restrict__ ccount, const float* __restrict__ size_emb,
                  const float* __restrict__ pos_enc, __hip_bfloat16* __restrict__ chunk)
{
    int m = blockIdx.x, b = blockIdx.y;
    int cnt = ccount[b * MAXC_ + m];
    for (int d = threadIdx.x; d < D_; d += 256) {
        float v;
        if (cnt > 0) {
            int first = cfirst[b * MAXC_ + m];
            float ssum = 0.f;
            for (int t = 0; t < cnt; ++t)
                ssum += attn_out[((long long)(b * S_ + first + t)) * D_ + d];
            float mean = ssum / (float)cnt;
            int clen = min(cnt, 1023);
            v = mean + size_emb[(long long)clen * D_ + d];
        } else {
            v = 0.f;
        }
        v += pos_enc[m * D_ + d];
        chunk[((long long)(b * MAXC_ + m)) * D_ + d] = __float2bfloat16(v);
    }
}

__global__ __launch_bounds__(256)
void ln_kernel(const float* __restrict__ y0, const float* __restrict__ g,
               const float* __restrict__ bb, float* __restrict__ out)
{
    int r = blockIdx.x;
    const float* row = y0 + (long long)r * D_;
    float loc[6];
    float s = 0.f;
    #pragma unroll
    for (int i = 0; i < 6; ++i) { loc[i] = row[threadIdx.x + i * 256]; s += loc[i]; }
    __shared__ float red[256];
    red[threadIdx.x] = s; __syncthreads();
    for (int o = 128; o; o >>= 1) { if (threadIdx.x < o) red[threadIdx.x] += red[threadIdx.x + o]; __syncthreads(); }
    float mu = red[0] / 1536.0f;
    __syncthreads();
    float s2 = 0.f;
    #pragma unroll
    for (int i = 0; i < 6; ++i) { float d = loc[i] - mu; s2 += d * d; }
    red[threadIdx.x] = s2; __syncthreads();
    for (int o = 128; o; o >>= 1) { if (threadIdx.x < o) red[threadIdx.x] += red[threadIdx.x + o]; __syncthreads(); }
    float var = red[0] / 1536.0f;
    float inv = 1.0f / sqrtf(var + 1e-5f);
    #pragma unroll
    for (int i = 0; i < 6; ++i) {
        int d = threadIdx.x + i * 256;
        out[(long long)r * D_ + d] = (loc[i] - mu) * inv * g[d] + bb[d];
    }
}

extern "C" void kernel_launch(void* const* d_in, const int* in_sizes, int n_in,
                              void* d_out, int out_size, void* d_ws, size_t ws_size,
                              hipStream_t stream)
{
    const float* x         = (const float*)d_in[0];
    const float* Wp        = (const float*)d_in[1];
    const float* bp        = (const float*)d_in[2];
    const float* detW1     = (const float*)d_in[3];
    const float* detb1     = (const float*)d_in[4];
    const float* detW2     = (const float*)d_in[5];
    const float* detb2     = (const float*)d_in[6];
    const float* detW3     = (const float*)d_in[7];
    const float* detb3     = (const float*)d_in[8];
    const float* in_proj_w = (const float*)d_in[9];
    const float* in_proj_b = (const float*)d_in[10];
    const float* out_w     = (const float*)d_in[11];
    const float* out_b     = (const float*)d_in[12];
    const float* size_emb  = (const float*)d_in[13];
    const float* pos_enc   = (const float*)d_in[14];
    const float* procW1    = (const float*)d_in[15];
    const float* procb1    = (const float*)d_in[16];
    const float* procW2    = (const float*)d_in[17];
    const float* procb2    = (const float*)d_in[18];
    const float* ln_g      = (const float*)d_in[19];
    const float* ln_b      = (const float*)d_in[20];
    float* out = (float*)d_out;

    const bool big = ws_size >= (size_t)192 * 1024 * 1024;

    char* ws = (char*)d_ws;
    // --- common det-phase ---
    float*          xlingf = (float*)(ws + 0);                  // 25.17 MB, dead after cs
    __hip_bfloat16* Wph    = (__hip_bfloat16*)(ws + 25165824);  // 4.72 MB
    __hip_bfloat16* Wpl    = (__hip_bfloat16*)(ws + 29884416);  // 4.72 MB
    __hip_bfloat16* h1h    = (__hip_bfloat16*)(ws + 0);         // 37.75 MB (after cs)
    __hip_bfloat16* h1l    = (__hip_bfloat16*)(ws + 37748736);  // 37.75 MB
    // --- small path ---
    __hip_bfloat16* W1h_s  = (__hip_bfloat16*)(ws + 75497472);  // 18.87 MB (2 slices)
    __hip_bfloat16* W1l_s  = (__hip_bfloat16*)(ws + 94371840);  // 18.87 MB
    __hip_bfloat16* W2h_s  = (__hip_bfloat16*)(ws + 75497472);  // 7.08 MB (after h1)
    __hip_bfloat16* W2l_s  = (__hip_bfloat16*)(ws + 82575360);  // 7.08 MB
    // --- big path ---
    __hip_bfloat16* xh     = (__hip_bfloat16*)(ws + 75497472);  // 12.58 MB
    __hip_bfloat16* xl     = (__hip_bfloat16*)(ws + 88082432);  // 12.58 MB
    __hip_bfloat16* W1h_b  = (__hip_bfloat16*)(ws + 125829120); // 28.31 MB (3 slices)
    __hip_bfloat16* W1l_b  = (__hip_bfloat16*)(ws + 154140672); // 28.31 MB
    __hip_bfloat16* W2h_b  = (__hip_bfloat16*)(ws + 125829120); // 7.08 MB (after h1)
    __hip_bfloat16* W2l_b  = (__hip_bfloat16*)(ws + 132907008); // 7.08 MB
    // --- continuous phase ---
    __hip_bfloat16* xb_s       = (__hip_bfloat16*)(ws + 0);
    __hip_bfloat16* in_proj_wb = (__hip_bfloat16*)(ws + 12582912);
    __hip_bfloat16* qkvb       = (__hip_bfloat16*)(ws + 26738688);
    __hip_bfloat16* ctxb       = (__hip_bfloat16*)(ws + 64487424);
    __hip_bfloat16* out_wb     = (__hip_bfloat16*)(ws + 12582912);
    float*          attno      = (float*)(ws + 77070336);
    __hip_bfloat16* chunkb     = (__hip_bfloat16*)(ws + 0);
    __hip_bfloat16* procW1b    = (__hip_bfloat16*)(ws + 3145728);
    __hip_bfloat16* hmidb      = (__hip_bfloat16*)(ws + 12582912);
    __hip_bfloat16* procW2b    = (__hip_bfloat16*)(ws + 18874368);
    float*          y0         = (float*)(ws + 28311552);
    // --- small persistent ---
    char* sm = ws + 113246208;
    float* csb    = (float*)(sm + 0);
    float* logits = (float*)(sm + 28672);
    float* fin    = (float*)(sm + 77824);
    int*   seg    = (int*)  (sm + 94208);
    int*   sstart = (int*)  (sm + 110592);
    int*   send   = (int*)  (sm + 126976);
    int*   cfirst = (int*)  (sm + 143360);
    int*   ccount = (int*)  (sm + 147456);

    const long long SLICE_W1 = 4718592LL;   // 1536*3072
    const long long SLICE_W2 = 1179648LL;   // 768*1536
    const long long H1_Z     = 6291456LL;   // 4096*1536

    // 0) pre-splits
    split_kernel<<<(2359296 / 4 + 255) / 256, 256, 0, stream>>>(Wp, Wph, Wpl, 2359296 / 4);
    if (big)
        split_kernel<<<(6291456 / 4 + 255) / 256, 256, 0, stream>>>(x, xh, xl, 6291456 / 4);

    // 1) x_ling via split-bf16 MFMA + cosine sims (DBUF=1: small grid / short K)
    if (big)
        mfma3_gemm<128, 0, 0, 0, 0, 1><<<dim3(12, 32, 1), 256, 0, stream>>>(
            nullptr, xh, xl, nullptr, Wph, Wpl, bp, 0,
            xlingf, nullptr, nullptr, nullptr, nullptr,
            1536, 1536, 1536, 1536, 0LL, 0LL, 0LL, 0LL);
    else
        mfma3_gemm<64, 1, 0, 0, 0, 1><<<dim3(12, 64, 1), 256, 0, stream>>>(
            x, nullptr, nullptr, nullptr, Wph, Wpl, bp, 0,
            xlingf, nullptr, nullptr, nullptr, nullptr,
            1536, 1536, 1536, 1536, 6291456LL, 0LL, 0LL, 0LL);
    cs_kernel<<<dim3(1789, 4), 64, 0, stream>>>(xlingf, csb);

    // 2) detector h1 (DBUF=0: proven 410us structure — LDS 32KB, 2 barriers)
    if (big) {
        split_kernel<<<(14155776 / 4 + 255) / 256, 256, 0, stream>>>(detW1, W1h_b, W1l_b, 14155776 / 4);
        mfma3_gemm<128, 0, 0, 1, 1, 0><<<dim3(12, 32, 3), 256, 0, stream>>>(
            nullptr, xh, xl, nullptr, W1h_b, W1l_b, detb1, 1536,
            nullptr, h1h, h1l, nullptr, nullptr,
            3072, 1536, 3072, 1536, 0LL, 0LL, SLICE_W1, H1_Z);
    } else {
        split_kernel<<<(2 * 4718592 / 4 + 255) / 256, 256, 0, stream>>>(detW1, W1h_s, W1l_s, 2 * 4718592 / 4);
        mfma3_gemm<128, 1, 0, 1, 1, 0><<<dim3(12, 32, 2), 256, 0, stream>>>(
            x, nullptr, nullptr, nullptr, W1h_s, W1l_s, detb1, 1536,
            nullptr, h1h, h1l, nullptr, nullptr,
            3072, 1536, 3072, 1536, 6291456LL, 0LL, SLICE_W1, H1_Z);
        split_kernel<<<(4718592 / 4 + 255) / 256, 256, 0, stream>>>(detW1 + 2 * SLICE_W1, W1h_s, W1l_s, 4718592 / 4);
        mfma3_gemm<64, 1, 0, 1, 1, 0><<<dim3(12, 64, 1), 256, 0, stream>>>(
            x, nullptr, nullptr, nullptr, W1h_s, W1l_s, detb1 + 2 * 1536, 1536,
            nullptr, h1h + 2 * H1_Z, h1l + 2 * H1_Z, nullptr, nullptr,
            3072, 1536, 3072, 1536, 6291456LL, 0LL, 0LL, 0LL);
    }

    // 3) detector h2 + fused logit dot (DBUF=1)
    __hip_bfloat16* W2h = big ? W2h_b : W2h_s;
    __hip_bfloat16* W2l = big ? W2l_b : W2l_s;
    split_kernel<<<(3538944 / 4 + 255) / 256, 256, 0, stream>>>(detW2, W2h, W2l, 3538944 / 4);
    hipMemsetAsync(logits, 0, 3 * 4096 * sizeof(float), stream);
    mfma3_gemm<128, 0, 0, 1, 2, 1><<<dim3(6, 32, 3), 256, 0, stream>>>(
        nullptr, h1h, h1l, nullptr, W2h, W2l, detb2, 768,
        nullptr, nullptr, nullptr, detW3, logits,
        1536, 1536, 1536, 768, 0LL, H1_Z, SLICE_W2, 4096LL);

    // 4) boundaries + segments
    final_kernel<<<16, 256, 0, stream>>>(csb, logits, detb3, fin);
    seg_kernel<<<4, 64, 0, stream>>>(fin, seg);
    hipMemsetAsync(ccount, 0, B_ * MAXC_ * sizeof(int), stream);
    segrange_kernel<<<16, 256, 0, stream>>>(fin, seg, sstart, send, cfirst, ccount);

    // 5) qkv projection (bf16 MFMA, global_load_lds staging)
    const __hip_bfloat16* xbf;
    if (big) {
        xbf = xh;  // identical to f2b(x)
    } else {
        f2b_kernel<<<(4096 * 1536 / 4 + 255) / 256, 256, 0, stream>>>(x, xb_s, 4096 * 1536 / 4);
        xbf = xb_s;
    }
    f2b_kernel<<<(4608 * 1536 / 4 + 255) / 256, 256, 0, stream>>>(in_proj_w, in_proj_wb, 4608 * 1536 / 4);
    mfma_gemm<0, 1><<<dim3(36, 32), 256, 0, stream>>>(xbf, in_proj_wb, in_proj_b, qkvb, 4096, 4608, 1536);

    // 6) block-diagonal attention (4 heads per block)
    attn_kernel<<<dim3(4096, 3), dim3(64, 4), 0, stream>>>(qkvb, sstart, send, ctxb);

    // 7) output projection
    f2b_kernel<<<(1536 * 1536 / 4 + 255) / 256, 256, 0, stream>>>(out_w, out_wb, 1536 * 1536 / 4);
    mfma_gemm<0, 0><<<dim3(12, 32), 256, 0, stream>>>(ctxb, out_wb, out_b, attno, 4096, 1536, 1536);

    // 8) chunk means + size emb + pos enc
    chunk_kernel<<<dim3(256, 4), 256, 0, stream>>>(attno, cfirst, ccount, size_emb, pos_enc, chunkb);

    // 9) chunk MLP
    f2b_kernel<<<(3072 * 1536 / 4 + 255) / 256, 256, 0, stream>>>(procW1, procW1b, 3072 * 1536 / 4);
    mfma_gemm<1, 1><<<dim3(24, 8), 256, 0, stream>>>(chunkb, procW1b, procb1, hmidb, 1024, 3072, 1536);
    f2b_kernel<<<(1536 * 3072 / 4 + 255) / 256, 256, 0, stream>>>(procW2, procW2b, 1536 * 3072 / 4);
    mfma_gemm<0, 0><<<dim3(12, 8), 256, 0, stream>>>(hmidb, procW2b, procb2, y0, 1024, 1536, 3072);

    // 10) layernorm -> output
    ln_kernel<<<1024, 256, 0, stream>>>(y0, ln_g, ln_b, out);
}